// Round 10
// baseline (359.933 us; speedup 1.0000x reference)
//
#include <hip/hip_runtime.h>

// GeneralizedInteractionNet on MI355X (gfx950). R10: all 3 layers fused in
// one kernel; one batch element per wave; zero barriers.
//
// Per layer:  M[n,D,d] = W[n,D,d]*h[n,d]
//   GEMM1: C[i,D] = sum_d Bi[b,i,d] * M[n,D,d]
//   GEMM2: R[i,D] = sum_f AT[n,i,f] * B0T[b,D,f]^T
//   out[b,n,D] = sum_i C[i,D]*R[i,D]
// i padded 40->64 (2 row tiles of 32); f padded 40->48 (3 K-steps of 16).
// Padding garbage annihilated by exact zeros in AT (rows i>=40, cols f>=40).
//
// R9 post-mortem: 2 b/wave needed 168 VGPRs of "wave-constant" frags; at
// VGPR_Count=108 the compiler RELOADED aBi/bT from L2 every n-iter ->
// exposed L2 latency = the 60% idle (MfmaUtil 40%). R10: layer recurrence
// is per-b independent -> fuse layers, wave owns one b end-to-end.
// Intermediate Bi lives in the wave's PRIVATE LDS patch (40x72 bf16,
// written per n, read back as next layer's A-frags; in-wave dep only ->
// no __syncthreads in the entire kernel). Wave-constants drop to 56 regs;
// total ~196 <= 256 @ (128,2): everything stays resident + prefetch slack.
// Per-n M[n]/AT[n] (14 KB) is read by all waves in loose lockstep -> L1
// serves most of it (14 KB << 32 KB L1/CU). 2 launches total.

typedef __bf16 bf16x8 __attribute__((ext_vector_type(8)));
typedef float  f32x16 __attribute__((ext_vector_type(16)));
typedef unsigned short us4 __attribute__((ext_vector_type(4)));

constexpr int BATCH = 2048;
constexpr int FDIM  = 40;
constexpr int DDIM  = 64;
constexpr int LAY   = 3;
constexpr int IPAD  = 64;   // i padded: 2 row-tiles of 32
constexpr int FPAD  = 48;   // f padded: 3 K-steps of 16
constexpr int LROW  = 72;   // LDS transpose row stride (elems); 144 B rows

__device__ __forceinline__ unsigned short f2bf(float f) {
  union { float f; unsigned u; } v; v.f = f;
  unsigned r = v.u + 0x7fff + ((v.u >> 16) & 1);   // round-to-nearest-even
  return (unsigned short)(r >> 16);
}

// Vectorized prep (4 elems/thread, ushort4 writes):
//  M[l,n,D,d]  = W*h (bf16, natural layout)
//  AT[l,n,i64,f48] = alpha[l,f,i,n], zero-padded (i>=40 or f>=40 -> 0)
//  B0b[b,f,d]  = bf16(inputs)          (layer-0 A operand)
//  B0T[b,d,f48]= bf16(inputs[b,f,d]), f>=40 -> 0   (GEMM2 B operand)
__global__ void prep_k(const float* __restrict__ W, const float* __restrict__ h,
                       const float* __restrict__ alpha, const float* __restrict__ inputs,
                       unsigned short* __restrict__ M, unsigned short* __restrict__ AT,
                       unsigned short* __restrict__ B0b, unsigned short* __restrict__ B0T) {
  int j = blockIdx.x * blockDim.x + threadIdx.x;
  const int nM4 = LAY * FDIM * DDIM * DDIM / 4;    // 122880
  const int nA4 = LAY * FDIM * IPAD * FPAD / 4;    // 92160
  const int nB4 = BATCH * FDIM * DDIM / 4;         // 1310720
  const int nT4 = BATCH * DDIM * FPAD / 4;         // 1572864
  if (j < nM4) {
    int e  = j * 4;
    int d  = e & 63;
    int ln = e >> 12;
    float4 wv = *reinterpret_cast<const float4*>(W + e);
    float4 hv = *reinterpret_cast<const float4*>(h + ln * DDIM + d);
    us4 o = { f2bf(wv.x * hv.x), f2bf(wv.y * hv.y), f2bf(wv.z * hv.z), f2bf(wv.w * hv.w) };
    *reinterpret_cast<us4*>(M + e) = o;
    return;
  }
  j -= nM4;
  if (j < nA4) {
    int e  = j * 4;
    int f  = e % FPAD;
    int ii = (e / FPAD) % IPAD;
    int n  = (e / (FPAD * IPAD)) % FDIM;
    int l  = e / (FPAD * IPAD * FDIM);
    us4 o = {0, 0, 0, 0};
    if (ii < FDIM) {
#pragma unroll
      for (int k = 0; k < 4; ++k)
        if (f + k < FDIM)
          o[k] = f2bf(alpha[(((size_t)l * FDIM + f + k) * FDIM + ii) * FDIM + n]);
    }
    *reinterpret_cast<us4*>(AT + e) = o;
    return;
  }
  j -= nA4;
  if (j < nB4) {
    int e = j * 4;
    float4 v = *reinterpret_cast<const float4*>(inputs + e);
    us4 o = { f2bf(v.x), f2bf(v.y), f2bf(v.z), f2bf(v.w) };
    *reinterpret_cast<us4*>(B0b + e) = o;
    return;
  }
  j -= nB4;
  if (j >= nT4) return;
  {
    int e  = j * 4;
    int f  = e % FPAD;
    int d  = (e / FPAD) % DDIM;
    int b  = e / (FPAD * DDIM);
    us4 o = {0, 0, 0, 0};
#pragma unroll
    for (int k = 0; k < 4; ++k)
      if (f + k < FDIM)
        o[k] = f2bf(inputs[((size_t)b * FDIM + f + k) * DDIM + d]);
    *reinterpret_cast<us4*>(B0T + e) = o;
  }
}

// mfma_f32_32x32x16_bf16 conventions:
//   A[m=lane&31][k=8*(lane>>5)+j]  B[k=8*(lane>>5)+j][col=lane&31]
//   C/D: col=lane&31, row=(reg&3)+8*(reg>>2)+4*(lane>>5)   [HW-verified]
__global__ __launch_bounds__(128, 2) void fused_k(
    const unsigned short* __restrict__ B0b,  // bf16 [B][40][64]
    const unsigned short* __restrict__ B0T,  // bf16 [B][64][48]
    const unsigned short* __restrict__ Mt,   // [3][40][64][64] bf16
    const unsigned short* __restrict__ ATt,  // [3][40][64][48] bf16 zero-padded
    float* __restrict__ outp)                // f32 [B][40][64]
{
  // Per-wave private transpose patch; in-wave dependency only -> NO barriers.
  __shared__ __align__(16) unsigned short xpose[2][FDIM * LROW];

  const int tid  = threadIdx.x;
  const int lane = tid & 63;
  const int w    = tid >> 6;                  // wave in block (0,1)
  const int c    = lane & 31;
  const int h    = lane >> 5;
  const int b    = blockIdx.x * 2 + w;        // this wave's batch element
  unsigned short* myL = xpose[w];

  // bT[dt][ks]: GEMM2 B = B0T[b][D][f] -- constant across ALL layers and n.
  bf16x8 bT[2][3];
#pragma unroll
  for (int dt = 0; dt < 2; ++dt)
#pragma unroll
    for (int ks = 0; ks < 3; ++ks)
      bT[dt][ks] = *reinterpret_cast<const bf16x8*>(
          B0T + ((size_t)b * DDIM + dt * 32 + c) * FPAD + ks * 16 + h * 8);

  // aBi[it][ks]: GEMM1 A for the current layer; layer 0 from global B0b.
  // Rows >=40 clamped to 39 (finite; killed by AT zero rows in aR).
  bf16x8 aBi[2][4];
#pragma unroll
  for (int it = 0; it < 2; ++it) {
    int row = it * 32 + c; if (row > FDIM - 1) row = FDIM - 1;
#pragma unroll
    for (int ks = 0; ks < 4; ++ks)
      aBi[it][ks] = *reinterpret_cast<const bf16x8*>(
          B0b + ((size_t)b * FDIM + row) * DDIM + ks * 16 + h * 8);
  }

  for (int l = 0; l < LAY; ++l) {
    const unsigned short* Ml = Mt  + l * (FDIM * DDIM * DDIM);
    const unsigned short* Al = ATt + l * (FDIM * IPAD * FPAD);

    if (l > 0) {
      // Refill aBi from the wave's LDS patch (prev layer's output,
      // transposed: row i, cols d contiguous). 8 ds_read_b128, once/layer.
#pragma unroll
      for (int it = 0; it < 2; ++it) {
        int row = it * 32 + c; if (row > FDIM - 1) row = FDIM - 1;
#pragma unroll
        for (int ks = 0; ks < 4; ++ks)
          aBi[it][ks] = *reinterpret_cast<const bf16x8*>(
              (const char*)myL + row * (LROW * 2) + ks * 32 + h * 16);
      }
    }

    for (int n = 0; n < FDIM; ++n) {
      const unsigned short* Mn = Ml + n * (DDIM * DDIM);
      const unsigned short* An = Al + n * (IPAD * FPAD);

      // Per-n operands: 14 contiguous b128 loads (L1-served: all waves on a
      // CU walk the same n-stream; 14 KB << 32 KB L1).
      bf16x8 mb[2][4];
#pragma unroll
      for (int dt = 0; dt < 2; ++dt)
#pragma unroll
        for (int ks = 0; ks < 4; ++ks)
          mb[dt][ks] = *reinterpret_cast<const bf16x8*>(
              Mn + (dt * 32 + c) * DDIM + ks * 16 + h * 8);
      bf16x8 at[2][3];
#pragma unroll
      for (int it = 0; it < 2; ++it)
#pragma unroll
        for (int ks = 0; ks < 3; ++ks)
          at[it][ks] = *reinterpret_cast<const bf16x8*>(
              An + (it * 32 + c) * FPAD + ks * 16 + h * 8);

      float pout[2] = {0.f, 0.f};   // [dt]
#pragma unroll
      for (int it = 0; it < 2; ++it) {
        // 4 independent MFMA chains (dt-interleaved) keep the pipe fed.
        f32x16 aC0 = {0,0,0,0,0,0,0,0,0,0,0,0,0,0,0,0};
        f32x16 aC1 = {0,0,0,0,0,0,0,0,0,0,0,0,0,0,0,0};
        f32x16 aR0 = {0,0,0,0,0,0,0,0,0,0,0,0,0,0,0,0};
        f32x16 aR1 = {0,0,0,0,0,0,0,0,0,0,0,0,0,0,0,0};
#pragma unroll
        for (int ks = 0; ks < 4; ++ks) {
          aC0 = __builtin_amdgcn_mfma_f32_32x32x16_bf16(aBi[it][ks], mb[0][ks], aC0, 0, 0, 0);
          aC1 = __builtin_amdgcn_mfma_f32_32x32x16_bf16(aBi[it][ks], mb[1][ks], aC1, 0, 0, 0);
        }
#pragma unroll
        for (int ks = 0; ks < 3; ++ks) {
          aR0 = __builtin_amdgcn_mfma_f32_32x32x16_bf16(at[it][ks], bT[0][ks], aR0, 0, 0, 0);
          aR1 = __builtin_amdgcn_mfma_f32_32x32x16_bf16(at[it][ks], bT[1][ks], aR1, 0, 0, 0);
        }
        // Combine: 4 independent partial chains per dt (depth 4).
        {
          float t0 = 0.f, t1 = 0.f, t2 = 0.f, t3 = 0.f;
#pragma unroll
          for (int r = 0; r < 4; ++r) {
            t0 += aC0[r] * aR0[r];         t1 += aC0[r + 4] * aR0[r + 4];
            t2 += aC0[r + 8] * aR0[r + 8]; t3 += aC0[r + 12] * aR0[r + 12];
          }
          pout[0] += (t0 + t1) + (t2 + t3);
        }
        {
          float t0 = 0.f, t1 = 0.f, t2 = 0.f, t3 = 0.f;
#pragma unroll
          for (int r = 0; r < 4; ++r) {
            t0 += aC1[r] * aR1[r];         t1 += aC1[r + 4] * aR1[r + 4];
            t2 += aC1[r + 8] * aR1[r + 8]; t3 += aC1[r + 12] * aR1[r + 12];
          }
          pout[1] += (t0 + t1) + (t2 + t3);
        }
      }

      // Finish i-sum across lane halves; lane's value is D = lane.
      float v0 = pout[0] + __shfl_xor(pout[0], 32, 64);
      float v1 = pout[1] + __shfl_xor(pout[1], 32, 64);
      float val = h ? v1 : v0;
      if (l == LAY - 1) {
        outp[((size_t)b * FDIM + n) * DDIM + lane] = val;        // coalesced f32
      } else {
        myL[n * LROW + lane] = f2bf(val);    // 2 lanes/bank: conflict-free
      }
    }
  }
}

extern "C" void kernel_launch(void* const* d_in, const int* in_sizes, int n_in,
                              void* d_out, int out_size, void* d_ws, size_t ws_size,
                              hipStream_t stream) {
  const float* inputs = (const float*)d_in[0];  // [2048,40,64]
  const float* W      = (const float*)d_in[1];  // [3,40,64,64]
  const float* alpha  = (const float*)d_in[2];  // [3,40,40,40]
  const float* h      = (const float*)d_in[3];  // [3,40,64,1]

  char* ws = (char*)d_ws;
  const size_t S   = (size_t)BATCH * FDIM * DDIM * 2;   // 10.49 MB B0b
  const size_t ST  = (size_t)BATCH * DDIM * FPAD * 2;   // 12.58 MB B0T
  unsigned short* B0b = (unsigned short*)(ws);
  unsigned short* B0T = (unsigned short*)(ws + S);
  unsigned short* Mb  = (unsigned short*)(ws + S + ST);
  unsigned short* ATb = (unsigned short*)(ws + S + ST + (size_t)LAY * FDIM * DDIM * DDIM * 2);

  const int nPrep4 = (LAY * FDIM * DDIM * DDIM + LAY * FDIM * IPAD * FPAD
                    + BATCH * FDIM * DDIM + BATCH * DDIM * FPAD) / 4;
  prep_k<<<(nPrep4 + 255) / 256, 256, 0, stream>>>(W, h, alpha, inputs, Mb, ATb, B0b, B0T);

  fused_k<<<dim3(BATCH / 2), dim3(128), 0, stream>>>(B0b, B0T, Mb, ATb, (float*)d_out);
}